// Round 3
// baseline (601.577 us; speedup 1.0000x reference)
//
#include <hip/hip_runtime.h>
#include <hip/hip_bf16.h>

#define HID 256
#define K27 27

typedef __attribute__((ext_vector_type(8))) short bf16x8;
typedef __attribute__((ext_vector_type(4))) float f32x4;

static __device__ __forceinline__ unsigned short f2bf(float f) {
    union { float f; unsigned u; } v; v.f = f;
    return (unsigned short)((v.u + 0x7FFFu + ((v.u >> 16) & 1u)) >> 16);
}
// packs (lo,hi) -> one u32 of 2 bf16 via v_cvt_pk_bf16_f32
static __device__ __forceinline__ unsigned pack2bf(float lo, float hi) {
    __hip_bfloat162 t = __float22bfloat162_rn(make_float2(lo, hi));
    return *reinterpret_cast<unsigned*>(&t);
}

// v3: MFMA layer-2 with B fragments staged in LDS (pre-arranged in fragment
// order -> 1 ds_read_b128 each, conflict-free), T=2 tiles per iteration to
// amortize sW1 reads, gathers hoisted above the MFMA loop so their latency
// hides under layer-1 compute. k-map: fragment element e <-> j = kc*32+g+4e
// (same bijection for A and B => contraction correct independent of HW's
// internal slot->k order; validated by v2's pass).
__global__ __launch_bounds__(256, 4) void mapnet_v3(
    const float* __restrict__ pos,      // (P,3)
    const int*   __restrict__ mapping,  // (P,2)
    const float* __restrict__ feats,    // (3,512,512)
    const float* __restrict__ W1,       // (256,3)
    const float* __restrict__ b1,       // (256)
    const float* __restrict__ W2,       // (27,256)
    const float* __restrict__ b2,       // (27)
    float* __restrict__ out)            // (P)
{
    __shared__ float4  sW1[HID];        // {w0,w1,w2,b1}
    __shared__ bf16x8  sB[16][64];      // [kc*2+nt][lane] fragment-order W2^T

    const int tid = threadIdx.x;
    for (int i = tid; i < HID; i += 256)
        sW1[i] = make_float4(W1[3*i], W1[3*i+1], W1[3*i+2], b1[i]);

    for (int e = tid; e < 1024; e += 256) {
        const int kcnt = e >> 6, l = e & 63;
        const int kc = kcnt >> 1, nt = kcnt & 1;
        const int gg = l >> 4, cc = l & 15;
        const int n = nt*16 + cc;
        union { bf16x8 v; unsigned u[4]; } bb;
        #pragma unroll
        for (int i = 0; i < 4; ++i) {
            const int j0 = kc*32 + gg + 8*i;       // elem 2i -> j0, 2i+1 -> j0+4
            float f0 = 0.f, f1 = 0.f;
            if (n < K27) { f0 = W2[n*HID + j0]; f1 = W2[n*HID + j0 + 4]; }
            bb.u[i] = (unsigned)f2bf(f0) | ((unsigned)f2bf(f1) << 16);
        }
        sB[kcnt][l] = bb.v;
    }
    __syncthreads();

    const int lane = tid & 63, wid = tid >> 6;
    const int g = lane >> 4, col = lane & 15;

    const float b2A = b2[col];
    const float b2B = (col < K27 - 16) ? b2[16 + col] : 0.0f;
    const int kA = col;
    const int cA = kA/9, dyA = (kA%9)/3 - 1, dxA = (kA%9)%3 - 1;
    const int kB = min(16 + col, K27 - 1);          // clamp -> valid address; acc1==0 there
    const int cB = kB/9, dyB = (kB%9)/3 - 1, dxB = (kB%9)%3 - 1;

    const int w = blockIdx.x * 4 + wid;             // 0..4095

    for (int it = 0; it < 8; ++it) {
        const int tb0 = (w * 16 + it * 2) * 16;     // 16 tiles/wave, 2 per iter
        const int tb1 = tb0 + 16;

        const float p00 = pos[3*(tb0+col)], p01 = pos[3*(tb0+col)+1], p02 = pos[3*(tb0+col)+2];
        const float p10 = pos[3*(tb1+col)], p11 = pos[3*(tb1+col)+1], p12 = pos[3*(tb1+col)+2];

        // ---- gathers issued BEFORE the MFMA loop (latency hides under h) ----
        float fvA[2][4], fvB[2][4];
        #pragma unroll
        for (int tt = 0; tt < 2; ++tt) {
            const int tb = tt ? tb1 : tb0;
            #pragma unroll
            for (int r = 0; r < 4; ++r) {
                const int m = tb + g*4 + r;
                const int my = mapping[2*m], mx = mapping[2*m+1];
                int y  = my + dyA, x  = mx + dxA;
                int yc = min(max(y,0),511), xc = min(max(x,0),511);
                float f = feats[(cA*512+yc)*512+xc];
                fvA[tt][r] = (((unsigned)y < 512u) && ((unsigned)x < 512u)) ? f : 0.f;
                int y2 = my + dyB, x2 = mx + dxB;
                int yc2 = min(max(y2,0),511), xc2 = min(max(x2,0),511);
                float f2 = feats[(cB*512+yc2)*512+xc2];
                fvB[tt][r] = (((unsigned)y2 < 512u) && ((unsigned)x2 < 512u)) ? f2 : 0.f;
            }
        }

        f32x4 acc00 = {b2A,b2A,b2A,b2A}, acc01 = {b2B,b2B,b2B,b2B};
        f32x4 acc10 = {b2A,b2A,b2A,b2A}, acc11 = {b2B,b2B,b2B,b2B};

        #pragma unroll
        for (int kc = 0; kc < 8; ++kc) {
            union { bf16x8 v; unsigned u[4]; } a0, a1;
            #pragma unroll
            for (int i = 0; i < 4; ++i) {
                const float4 wA = sW1[kc*32 + g + 8*i];
                const float4 wB = sW1[kc*32 + g + 8*i + 4];
                float x00 = fmaf(p00,wA.x,fmaf(p01,wA.y,fmaf(p02,wA.z,wA.w)));
                float x01 = fmaf(p00,wB.x,fmaf(p01,wB.y,fmaf(p02,wB.z,wB.w)));
                float x10 = fmaf(p10,wA.x,fmaf(p11,wA.y,fmaf(p12,wA.z,wA.w)));
                float x11 = fmaf(p10,wB.x,fmaf(p11,wB.y,fmaf(p12,wB.z,wB.w)));
                x00 = fmaxf(x00, 0.01f*x00); x01 = fmaxf(x01, 0.01f*x01);
                x10 = fmaxf(x10, 0.01f*x10); x11 = fmaxf(x11, 0.01f*x11);
                a0.u[i] = pack2bf(x00, x01);
                a1.u[i] = pack2bf(x10, x11);
            }
            const bf16x8 bv0 = sB[kc*2    ][lane];
            const bf16x8 bv1 = sB[kc*2 + 1][lane];
            acc00 = __builtin_amdgcn_mfma_f32_16x16x32_bf16(a0.v, bv0, acc00, 0,0,0);
            acc01 = __builtin_amdgcn_mfma_f32_16x16x32_bf16(a0.v, bv1, acc01, 0,0,0);
            acc10 = __builtin_amdgcn_mfma_f32_16x16x32_bf16(a1.v, bv0, acc10, 0,0,0);
            acc11 = __builtin_amdgcn_mfma_f32_16x16x32_bf16(a1.v, bv1, acc11, 0,0,0);
        }

        // ---- combine: C/D layout col=lane&15 (k27), row=g*4+r (pixel) ----
        #pragma unroll
        for (int tt = 0; tt < 2; ++tt) {
            const int tb = tt ? tb1 : tb0;
            const f32x4 aA = tt ? acc10 : acc00;
            const f32x4 aB = tt ? acc11 : acc01;
            #pragma unroll
            for (int r = 0; r < 4; ++r) {
                float s = aA[r] * fvA[tt][r] + aB[r] * fvB[tt][r];
                s += __shfl_xor(s, 1);
                s += __shfl_xor(s, 2);
                s += __shfl_xor(s, 4);
                s += __shfl_xor(s, 8);
                if (col == r) out[tb + g*4 + r] = s;
            }
        }
    }
}

extern "C" void kernel_launch(void* const* d_in, const int* in_sizes, int n_in,
                              void* d_out, int out_size, void* d_ws, size_t ws_size,
                              hipStream_t stream) {
    const float* pos     = (const float*)d_in[0];
    const int*   mapping = (const int*)d_in[1];
    const float* feats   = (const float*)d_in[2];
    // d_in[3] = depth, unused
    const float* W1      = (const float*)d_in[4];
    const float* b1      = (const float*)d_in[5];
    const float* W2      = (const float*)d_in[6];
    const float* b2      = (const float*)d_in[7];
    float* out = (float*)d_out;

    // P = 1024*1024: 65536 tiles of 16 pixels; 1024 blocks x 4 waves x 16 tiles
    mapnet_v3<<<1024, 256, 0, stream>>>(pos, mapping, feats, W1, b1, W2, b2, out);
}

// Round 5
// 85.000 us; speedup vs baseline: 7.0774x; 7.0774x over previous
//
#include <hip/hip_runtime.h>

#define HID 256
#define K27 27

typedef __attribute__((ext_vector_type(8))) short    bf16x8;
typedef __attribute__((ext_vector_type(4))) float    f32x4;
typedef __attribute__((ext_vector_type(4))) unsigned u32x4;

static __device__ __forceinline__ unsigned short f2bf(float f) {
    union { float f; unsigned u; } v; v.f = f;   // cold path only (staging)
    return (unsigned short)((v.u + 0x7FFFu + ((v.u >> 16) & 1u)) >> 16);
}
// (lo,hi) -> one u32 holding 2 bf16, single v_cvt_pk_bf16_f32 (T12 recipe:
// no builtin on gfx950; inline asm keeps everything in VGPRs, no alloca)
static __device__ __forceinline__ unsigned pack2bf(float lo, float hi) {
    unsigned r;
    asm("v_cvt_pk_bf16_f32 %0, %1, %2" : "=v"(r) : "v"(lo), "v"(hi));
    return r;
}
static __device__ __forceinline__ bf16x8 as_bf16x8(u32x4 u) {
    return __builtin_bit_cast(bf16x8, u);
}

// v4b = v4 with the pack2bf compile fix (inline-asm v_cvt_pk_bf16_f32).
// Layer-2 as mfma_f32_16x16x32_bf16; B fragments (W2^T bf16) staged in LDS in
// exact fragment order (1 conflict-free ds_read_b128 each); layer-1 h computed
// in A-fragment layout from LDS-resident {W1|b1}; gathers hoisted above the
// MFMA loop so HBM/L2 latency hides under h-compute.
// k-map: fragment element e of lane-group g <-> j = kc*32 + g + 4e (same
// bijection for A and B => contraction correct regardless of HW slot order).
__global__ __launch_bounds__(256, 4) void mapnet_v4(
    const float* __restrict__ pos,      // (P,3)
    const int*   __restrict__ mapping,  // (P,2)
    const float* __restrict__ feats,    // (3,512,512)
    const float* __restrict__ W1,       // (256,3)
    const float* __restrict__ b1,       // (256)
    const float* __restrict__ W2,       // (27,256)
    const float* __restrict__ b2,       // (27)
    float* __restrict__ out)            // (P)
{
    __shared__ float4  sW1[HID];        // {w0,w1,w2,b1}
    __shared__ bf16x8  sB[16][64];      // [kc*2+nt][lane], fragment-order W2^T

    const int tid = threadIdx.x;
    for (int i = tid; i < HID; i += 256)
        sW1[i] = make_float4(W1[3*i], W1[3*i+1], W1[3*i+2], b1[i]);

    for (int e = tid; e < 1024; e += 256) {
        const int kcnt = e >> 6, l = e & 63;
        const int kc = kcnt >> 1, nt = kcnt & 1;
        const int gg = l >> 4, cc = l & 15;
        const int n = nt*16 + cc;
        u32x4 bb;
        #pragma unroll
        for (int i = 0; i < 4; ++i) {
            const int j0 = kc*32 + gg + 8*i;        // elem 2i -> j0, 2i+1 -> j0+4
            float f0 = 0.f, f1 = 0.f;
            if (n < K27) { f0 = W2[n*HID + j0]; f1 = W2[n*HID + j0 + 4]; }
            bb[i] = (unsigned)f2bf(f0) | ((unsigned)f2bf(f1) << 16);
        }
        sB[kcnt][l] = as_bf16x8(bb);
    }
    __syncthreads();

    const int lane = tid & 63, wid = tid >> 6;
    const int g = lane >> 4, col = lane & 15;

    const float b2A = b2[col];
    const float b2B = (col < K27 - 16) ? b2[16 + col] : 0.0f;
    const int kA = col;
    const int cA = kA/9, dyA = (kA%9)/3 - 1, dxA = (kA%9)%3 - 1;
    const int kB = min(16 + col, K27 - 1);          // clamped -> valid addr; acc1==0 there
    const int cB = kB/9, dyB = (kB%9)/3 - 1, dxB = (kB%9)%3 - 1;

    const int w = blockIdx.x * 4 + wid;             // 0..4095

    for (int it = 0; it < 8; ++it) {
        const int tb0 = (w * 16 + it * 2) * 16;     // 16 tiles/wave, 2/iter
        const int tb1 = tb0 + 16;

        const float p00 = pos[3*(tb0+col)], p01 = pos[3*(tb0+col)+1], p02 = pos[3*(tb0+col)+2];
        const float p10 = pos[3*(tb1+col)], p11 = pos[3*(tb1+col)+1], p12 = pos[3*(tb1+col)+2];

        // ---- gathers issued BEFORE the MFMA loop (latency hides under h) ----
        float fvA[2][4], fvB[2][4];
        #pragma unroll
        for (int tt = 0; tt < 2; ++tt) {
            const int tb = tt ? tb1 : tb0;
            #pragma unroll
            for (int r = 0; r < 4; ++r) {
                const int m = tb + g*4 + r;
                const int my = mapping[2*m], mx = mapping[2*m+1];
                int y  = my + dyA, x  = mx + dxA;
                int yc = min(max(y,0),511), xc = min(max(x,0),511);
                float f = feats[(cA*512+yc)*512+xc];
                fvA[tt][r] = (((unsigned)y < 512u) && ((unsigned)x < 512u)) ? f : 0.f;
                int y2 = my + dyB, x2 = mx + dxB;
                int yc2 = min(max(y2,0),511), xc2 = min(max(x2,0),511);
                float f2 = feats[(cB*512+yc2)*512+xc2];
                fvB[tt][r] = (((unsigned)y2 < 512u) && ((unsigned)x2 < 512u)) ? f2 : 0.f;
            }
        }

        f32x4 acc00 = {b2A,b2A,b2A,b2A}, acc01 = {b2B,b2B,b2B,b2B};
        f32x4 acc10 = {b2A,b2A,b2A,b2A}, acc11 = {b2B,b2B,b2B,b2B};

        #pragma unroll
        for (int kc = 0; kc < 8; ++kc) {
            u32x4 a0, a1;
            #pragma unroll
            for (int i = 0; i < 4; ++i) {
                const float4 wA = sW1[kc*32 + g + 8*i];
                const float4 wB = sW1[kc*32 + g + 8*i + 4];
                float x00 = fmaf(p00,wA.x,fmaf(p01,wA.y,fmaf(p02,wA.z,wA.w)));
                float x01 = fmaf(p00,wB.x,fmaf(p01,wB.y,fmaf(p02,wB.z,wB.w)));
                float x10 = fmaf(p10,wA.x,fmaf(p11,wA.y,fmaf(p12,wA.z,wA.w)));
                float x11 = fmaf(p10,wB.x,fmaf(p11,wB.y,fmaf(p12,wB.z,wB.w)));
                x00 = fmaxf(x00, 0.01f*x00); x01 = fmaxf(x01, 0.01f*x01);
                x10 = fmaxf(x10, 0.01f*x10); x11 = fmaxf(x11, 0.01f*x11);
                a0[i] = pack2bf(x00, x01);
                a1[i] = pack2bf(x10, x11);
            }
            const bf16x8 av0 = as_bf16x8(a0);
            const bf16x8 av1 = as_bf16x8(a1);
            const bf16x8 bv0 = sB[kc*2    ][lane];
            const bf16x8 bv1 = sB[kc*2 + 1][lane];
            acc00 = __builtin_amdgcn_mfma_f32_16x16x32_bf16(av0, bv0, acc00, 0,0,0);
            acc01 = __builtin_amdgcn_mfma_f32_16x16x32_bf16(av0, bv1, acc01, 0,0,0);
            acc10 = __builtin_amdgcn_mfma_f32_16x16x32_bf16(av1, bv0, acc10, 0,0,0);
            acc11 = __builtin_amdgcn_mfma_f32_16x16x32_bf16(av1, bv1, acc11, 0,0,0);
        }

        // ---- combine: C/D layout col=lane&15 (k27), row=g*4+r (pixel) ----
        #pragma unroll
        for (int tt = 0; tt < 2; ++tt) {
            const int tb = tt ? tb1 : tb0;
            const f32x4 aA = tt ? acc10 : acc00;
            const f32x4 aB = tt ? acc11 : acc01;
            #pragma unroll
            for (int r = 0; r < 4; ++r) {
                float s = aA[r] * fvA[tt][r] + aB[r] * fvB[tt][r];
                s += __shfl_xor(s, 1);
                s += __shfl_xor(s, 2);
                s += __shfl_xor(s, 4);
                s += __shfl_xor(s, 8);
                if (col == r) out[tb + g*4 + r] = s;
            }
        }
    }
}

extern "C" void kernel_launch(void* const* d_in, const int* in_sizes, int n_in,
                              void* d_out, int out_size, void* d_ws, size_t ws_size,
                              hipStream_t stream) {
    const float* pos     = (const float*)d_in[0];
    const int*   mapping = (const int*)d_in[1];
    const float* feats   = (const float*)d_in[2];
    // d_in[3] = depth, unused
    const float* W1      = (const float*)d_in[4];
    const float* b1      = (const float*)d_in[5];
    const float* W2      = (const float*)d_in[6];
    const float* b2      = (const float*)d_in[7];
    float* out = (float*)d_out;

    // P = 1024*1024: 65536 tiles of 16 pixels; 1024 blocks x 4 waves x 16 tiles
    mapnet_v4<<<1024, 256, 0, stream>>>(pos, mapping, feats, W1, b1, W2, b2, out);
}